// Round 7
// baseline (117.023 us; speedup 1.0000x reference)
//
#include <hip/hip_runtime.h>

// TRecPolicy round 7: round-6 dot2 kernel with the h2 type fixed to __fp16
// (matches __builtin_amdgcn_cvt_pkrtz return / __builtin_amdgcn_fdot2 operand).

typedef float v2f __attribute__((ext_vector_type(2)));
typedef __fp16 h2 __attribute__((ext_vector_type(2)));

__device__ __forceinline__ v2f mk2(float a, float b) { v2f r; r.x = a; r.y = b; return r; }
__device__ __forceinline__ v2f spl(float s) { return mk2(s, s); }
__device__ __forceinline__ v2f fma2(v2f a, v2f b, v2f c) { return __builtin_elementwise_fma(a, b, c); }

__device__ __forceinline__ float fexp2(float x) {
#if __has_builtin(__builtin_amdgcn_exp2f)
    return __builtin_amdgcn_exp2f(x);          // v_exp_f32 (2^x)
#else
    return __expf(0.6931471805599453f * x);
#endif
}
__device__ __forceinline__ float frcp(float x) { return __builtin_amdgcn_rcpf(x); }

#define LOG2E 1.44269504088896f

__device__ __forceinline__ v2f sig2(v2f g) {           // 1/(1+2^(-x*log2e))
    v2f t = g * spl(-LOG2E);
    v2f e = mk2(fexp2(t.x), fexp2(t.y));
    v2f d = e + spl(1.0f);
    return mk2(frcp(d.x), frcp(d.y));
}
__device__ __forceinline__ v2f tanh2(v2f g) {          // 2/(1+2^(-2x*log2e)) - 1
    v2f t = g * spl(-2.0f * LOG2E);
    v2f e = mk2(fexp2(t.x), fexp2(t.y));
    v2f d = e + spl(1.0f);
    v2f r = mk2(frcp(d.x), frcp(d.y));
    return fma2(r, spl(2.0f), spl(-1.0f));
}

__device__ __forceinline__ float fdot2(h2 a, h2 b, float c) {
#if __has_builtin(__builtin_amdgcn_fdot2)
    return __builtin_amdgcn_fdot2(a, b, c, false);     // v_dot2_f32_f16
#else
    return fmaf((float)a.x, (float)b.x, fmaf((float)a.y, (float)b.y, c));
#endif
}
__device__ __forceinline__ h2 pkh(float a, float b) {
    return __builtin_amdgcn_cvt_pkrtz(a, b);           // v_cvt_pkrtz_f16_f32
}

// Packed parameter block in d_ws:
//   float sb[42]  : scalar biases (pre-summed where possible) + wo4 + bo
//   h2    wh[110] : all weights as half2 pairs in consumption order
// sb: [0..7] b_ih_up+b_hh_up rows0..7 | [8..15] b_ih_dn+b_hh_dn rows0..7
//     [16..19] b_ih_up rows8..11 | [20..23] b_hh_up rows8..11
//     [24..27] b_ih_dn rows8..11 | [28..31] b_hh_dn rows8..11
//     [32..35] b1 | [36..39] b2 | [40] w_out[4] | [41] b_out[0]
// wh: [0..11]   wiu(k)   = {w_ih_up[2k], w_ih_up[2k+1]}
//     [12..35]  whu(k,e) = {w_hh_up[4k+2e], w_hh_up[4k+2e+1]}
//     [36..59]  wid(k,e) = {w_ih_dn[4k+2e], w_ih_dn[4k+2e+1]}
//     [60..83]  whd(k,e) = {w_hh_dn[4k+2e], w_hh_dn[4k+2e+1]}
//     [84..99]  w1h(k,c) = {w1[8k+2c], w1[8k+2c+1]}
//     [100..107]w2h(k,c) = {w2[4k+2c], w2[4k+2c+1]}
//     [108..109]woh(c)   = {w_out[2c], w_out[2c+1]}

__global__ void repack_kernel(
    const float* __restrict__ w_ih_up, const float* __restrict__ w_hh_up,
    const float* __restrict__ b_ih_up, const float* __restrict__ b_hh_up,
    const float* __restrict__ w1, const float* __restrict__ b1,
    const float* __restrict__ w2, const float* __restrict__ b2,
    const float* __restrict__ w_ih_dn, const float* __restrict__ w_hh_dn,
    const float* __restrict__ b_ih_dn, const float* __restrict__ b_hh_dn,
    const float* __restrict__ w_out, const float* __restrict__ b_out,
    float* __restrict__ ws)
{
    const int t = threadIdx.x;
    if (t < 42) {
        float v;
        if      (t < 8)  v = b_ih_up[t] + b_hh_up[t];
        else if (t < 16) v = b_ih_dn[t - 8] + b_hh_dn[t - 8];
        else if (t < 20) v = b_ih_up[8 + t - 16];
        else if (t < 24) v = b_hh_up[8 + t - 20];
        else if (t < 28) v = b_ih_dn[8 + t - 24];
        else if (t < 32) v = b_hh_dn[8 + t - 28];
        else if (t < 36) v = b1[t - 32];
        else if (t < 40) v = b2[t - 36];
        else if (t == 40) v = w_out[4];
        else              v = b_out[0];
        ws[t] = v;
    } else if (t < 152) {
        const int u = t - 42;
        float a, b;
        if (u < 12)       { a = w_ih_up[2*u];                          b = w_ih_up[2*u + 1]; }
        else if (u < 36)  { int v = u - 12, k = v >> 1, e = v & 1;     a = w_hh_up[4*k + 2*e]; b = w_hh_up[4*k + 2*e + 1]; }
        else if (u < 60)  { int v = u - 36, k = v >> 1, e = v & 1;     a = w_ih_dn[4*k + 2*e]; b = w_ih_dn[4*k + 2*e + 1]; }
        else if (u < 84)  { int v = u - 60, k = v >> 1, e = v & 1;     a = w_hh_dn[4*k + 2*e]; b = w_hh_dn[4*k + 2*e + 1]; }
        else if (u < 100) { int v = u - 84, k = v >> 2, c = v & 3;     a = w1[8*k + 2*c];      b = w1[8*k + 2*c + 1]; }
        else if (u < 108) { int v = u - 100, k = v >> 1, c = v & 1;    a = w2[4*k + 2*c];      b = w2[4*k + 2*c + 1]; }
        else              { int c = u - 108;                           a = w_out[2*c];         b = w_out[2*c + 1]; }
        reinterpret_cast<h2*>(ws)[t] = pkh(a, b);
    }
}

__global__ void __launch_bounds__(256) trec_kernel(
    const float* __restrict__ x, const float* __restrict__ sb,
    float* __restrict__ out, int n)
{
    const int row = blockIdx.x * blockDim.x + threadIdx.x;
    if (row >= n) return;

    const h2* __restrict__ wh = reinterpret_cast<const h2*>(sb + 42);
    #define WIU(k)    wh[(k)]
    #define WHU(k,e)  wh[12 + 2*(k) + (e)]
    #define WID(k,e)  wh[36 + 2*(k) + (e)]
    #define WHD(k,e)  wh[60 + 2*(k) + (e)]
    #define W1H(k,c)  wh[84 + 4*(k) + (c)]
    #define W2H(k,c)  wh[100 + 2*(k) + (c)]
    #define WOH(c)    wh[108 + (c)]

    // ---- load 18-float row as 9x float2 ----
    float xv[18];
    {
        const float2* xp = reinterpret_cast<const float2*>(x + (size_t)row * 18u);
        #pragma unroll
        for (int k = 0; k < 9; ++k) {
            float2 v = xp[k];
            xv[2 * k] = v.x;
            xv[2 * k + 1] = v.y;
        }
    }
    // half2 {j[i], jd[i]} for the up-GRU x-part
    h2 xjh[7];
    #pragma unroll
    for (int i = 0; i < 7; ++i) xjh[i] = pkh(xv[4 + i], xv[11 + i]);

    v2f hA = spl(0.f), hB = spl(0.f);
    h2 h01 = pkh(0.f, 0.f), h23 = pkh(0.f, 0.f);
    h2 hup01[7], hup23[7];

    // ---- up GRU: i = 6..0, xi = [j[i], jd[i]] ----
    #pragma unroll
    for (int s = 0; s < 7; ++s) {
        const int i = 6 - s;
        const h2 xh = xjh[i];

        float g[8];
        #pragma unroll
        for (int k = 0; k < 8; ++k)
            g[k] = fdot2(h23, WHU(k, 1), fdot2(h01, WHU(k, 0), fdot2(xh, WIU(k), sb[k])));
        v2f rA = sig2(mk2(g[0], g[1])), rB = sig2(mk2(g[2], g[3]));
        v2f zA = sig2(mk2(g[4], g[5])), zB = sig2(mk2(g[6], g[7]));

        float gi[4], gh[4];
        #pragma unroll
        for (int k = 0; k < 4; ++k) {
            gi[k] = fdot2(xh, WIU(8 + k), sb[16 + k]);
            gh[k] = fdot2(h23, WHU(8 + k, 1), fdot2(h01, WHU(8 + k, 0), sb[20 + k]));
        }
        v2f nA = tanh2(fma2(rA, mk2(gh[0], gh[1]), mk2(gi[0], gi[1])));
        v2f nB = tanh2(fma2(rB, mk2(gh[2], gh[3]), mk2(gi[2], gi[3])));

        hA = fma2(zA, hA - nA, nA);            // (1-z)*n + z*h
        hB = fma2(zB, hB - nB, nB);
        h01 = pkh(hA.x, hA.y); h23 = pkh(hB.x, hB.y);
        hup01[s] = h01; hup23[s] = h23;
    }

    // ---- MLP: tanh([obs,h] @ w1.T + b1) -> tanh(@ w2.T + b2) ----
    {
        h2 o01 = pkh(xv[0], xv[1]), o23 = pkh(xv[2], xv[3]);
        float a[4];
        #pragma unroll
        for (int k = 0; k < 4; ++k)
            a[k] = fdot2(h23, W1H(k, 3), fdot2(h01, W1H(k, 2),
                    fdot2(o23, W1H(k, 1), fdot2(o01, W1H(k, 0), sb[32 + k]))));
        v2f t1A = tanh2(mk2(a[0], a[1])), t1B = tanh2(mk2(a[2], a[3]));
        h2 t01 = pkh(t1A.x, t1A.y), t23 = pkh(t1B.x, t1B.y);
        float c[4];
        #pragma unroll
        for (int k = 0; k < 4; ++k)
            c[k] = fdot2(t23, W2H(k, 1), fdot2(t01, W2H(k, 0), sb[36 + k]));
        hA = tanh2(mk2(c[0], c[1])); hB = tanh2(mk2(c[2], c[3]));
        h01 = pkh(hA.x, hA.y); h23 = pkh(hB.x, hB.y);
    }

    // ---- down GRU: i = 0..6, xi = hup[i]; act = [h, j[i]] @ w_out.T + b_out ----
    const float wo4 = sb[40], bo = sb[41];
    float acts[7];
    #pragma unroll
    for (int i = 0; i < 7; ++i) {
        const h2 xi01 = hup01[i], xi23 = hup23[i];

        float g[8];
        #pragma unroll
        for (int k = 0; k < 8; ++k)
            g[k] = fdot2(h23, WHD(k, 1), fdot2(h01, WHD(k, 0),
                    fdot2(xi23, WID(k, 1), fdot2(xi01, WID(k, 0), sb[8 + k]))));
        v2f rA = sig2(mk2(g[0], g[1])), rB = sig2(mk2(g[2], g[3]));
        v2f zA = sig2(mk2(g[4], g[5])), zB = sig2(mk2(g[6], g[7]));

        float gi[4], gh[4];
        #pragma unroll
        for (int k = 0; k < 4; ++k) {
            gi[k] = fdot2(xi23, WID(8 + k, 1), fdot2(xi01, WID(8 + k, 0), sb[24 + k]));
            gh[k] = fdot2(h23, WHD(8 + k, 1), fdot2(h01, WHD(8 + k, 0), sb[28 + k]));
        }
        v2f nA = tanh2(fma2(rA, mk2(gh[0], gh[1]), mk2(gi[0], gi[1])));
        v2f nB = tanh2(fma2(rB, mk2(gh[2], gh[3]), mk2(gi[2], gi[3])));

        hA = fma2(zA, hA - nA, nA);
        hB = fma2(zB, hB - nB, nB);
        h01 = pkh(hA.x, hA.y); h23 = pkh(hB.x, hB.y);

        acts[i] = fmaf(xv[4 + i], wo4, fdot2(h23, WOH(1), fdot2(h01, WOH(0), bo)));
    }

    // ---- store (n x 7, row-major) ----
    float* op = out + (size_t)row * 7u;
    #pragma unroll
    for (int i = 0; i < 7; ++i) op[i] = acts[i];

    #undef WIU
    #undef WHU
    #undef WID
    #undef WHD
    #undef W1H
    #undef W2H
    #undef WOH
}

extern "C" void kernel_launch(void* const* d_in, const int* in_sizes, int n_in,
                              void* d_out, int out_size, void* d_ws, size_t ws_size,
                              hipStream_t stream)
{
    const float* x       = (const float*)d_in[0];
    const float* w_ih_up = (const float*)d_in[1];
    const float* w_hh_up = (const float*)d_in[2];
    const float* b_ih_up = (const float*)d_in[3];
    const float* b_hh_up = (const float*)d_in[4];
    const float* w1      = (const float*)d_in[5];
    const float* b1      = (const float*)d_in[6];
    const float* w2      = (const float*)d_in[7];
    const float* b2      = (const float*)d_in[8];
    const float* w_ih_dn = (const float*)d_in[9];
    const float* w_hh_dn = (const float*)d_in[10];
    const float* b_ih_dn = (const float*)d_in[11];
    const float* b_hh_dn = (const float*)d_in[12];
    const float* w_out   = (const float*)d_in[13];
    const float* b_out   = (const float*)d_in[14];
    float* out = (float*)d_out;

    const int n = in_sizes[0] / 18;
    const int block = 256;
    const int grid = (n + block - 1) / block;

    repack_kernel<<<1, 192, 0, stream>>>(
        w_ih_up, w_hh_up, b_ih_up, b_hh_up,
        w1, b1, w2, b2,
        w_ih_dn, w_hh_dn, b_ih_dn, b_hh_dn,
        w_out, b_out, (float*)d_ws);

    trec_kernel<<<grid, block, 0, stream>>>(
        x, (const float*)d_ws, out, n);
}

// Round 8
// 105.836 us; speedup vs baseline: 1.1057x; 1.1057x over previous
//
#include <hip/hip_runtime.h>

// TRecPolicy round 8: round-5 packed-f32 kernel (best: 7337 cy/wave) with the
// activation pre-scales (-log2e / -2log2e) folded into the pre-packed weights
// and biases, removing one v_pk_mul per activation call (~90 pk ops/row).

typedef float v2f __attribute__((ext_vector_type(2)));

__device__ __forceinline__ v2f mk2(float a, float b) { v2f r; r.x = a; r.y = b; return r; }
__device__ __forceinline__ v2f spl(float s) { return mk2(s, s); }
__device__ __forceinline__ v2f fma2(v2f a, v2f b, v2f c) { return __builtin_elementwise_fma(a, b, c); }

__device__ __forceinline__ float fexp2(float x) {
#if __has_builtin(__builtin_amdgcn_exp2f)
    return __builtin_amdgcn_exp2f(x);          // v_exp_f32 (2^x)
#else
    return __expf(0.6931471805599453f * x);
#endif
}
__device__ __forceinline__ float frcp(float x) { return __builtin_amdgcn_rcpf(x); }

#define LOG2E 1.44269504088896f

// PRE-SCALED activations: input is already -log2e*x (sig) / -2log2e*x (tanh).
__device__ __forceinline__ v2f sig2s(v2f t) {          // 1/(1+2^t)
    v2f e = mk2(fexp2(t.x), fexp2(t.y));
    v2f d = e + spl(1.0f);
    return mk2(frcp(d.x), frcp(d.y));
}
__device__ __forceinline__ v2f tanh2s(v2f t) {         // 2/(1+2^t) - 1
    v2f e = mk2(fexp2(t.x), fexp2(t.y));
    v2f d = e + spl(1.0f);
    v2f r = mk2(frcp(d.x), frcp(d.y));
    return fma2(r, spl(2.0f), spl(-1.0f));
}

// Packed parameter block layout (all v2f, 131 total). Pair pp covers output
// rows (2pp, 2pp+1); element [pp][c] = scale * {W[2pp][c], W[2pp+1][c]}.
// Scales: gate rows 0..7 (r,z) -> -LOG2E; rows 8..11 (n) -> -2LOG2E;
//         w1/b1/w2/b2 -> -2LOG2E; w_out/b_out unscaled.
struct PK {
    v2f wiu[6][2];   // off   0: w_ih_up (12x2), scaled
    v2f whu[6][4];   // off  12: w_hh_up (12x4), scaled
    v2f wid[6][4];   // off  36: w_ih_dn (12x4), scaled
    v2f whd[6][4];   // off  60: w_hh_dn (12x4), scaled
    v2f w1p[2][8];   // off  84: w1 (4x8), scaled
    v2f w2p[2][4];   // off 100: w2 (4x4), scaled
    v2f bsu[4];      // off 108: (b_ih_up+b_hh_up) rows 0..7, scaled
    v2f bsd[4];      // off 112: (b_ih_dn+b_hh_dn) rows 0..7, scaled
    v2f binu[2];     // off 116: b_ih_up rows 8..11, scaled
    v2f bhnu[2];     // off 118: b_hh_up rows 8..11, scaled
    v2f bind[2];     // off 120: b_ih_dn rows 8..11, scaled
    v2f bhnd[2];     // off 122: b_hh_dn rows 8..11, scaled
    v2f b1p[2];      // off 124: scaled
    v2f b2p[2];      // off 126: scaled
    v2f wo01;        // off 128: {w_out[0], w_out[1]}
    v2f wo23;        // off 129: {w_out[2], w_out[3]}
    v2f wo4bo;       // off 130: {w_out[4], b_out[0]}
};

#define SRZ (-LOG2E)
#define SN  (-2.0f * LOG2E)

__global__ void repack_kernel(
    const float* __restrict__ w_ih_up, const float* __restrict__ w_hh_up,
    const float* __restrict__ b_ih_up, const float* __restrict__ b_hh_up,
    const float* __restrict__ w1, const float* __restrict__ b1,
    const float* __restrict__ w2, const float* __restrict__ b2,
    const float* __restrict__ w_ih_dn, const float* __restrict__ w_hh_dn,
    const float* __restrict__ b_ih_dn, const float* __restrict__ b_hh_dn,
    const float* __restrict__ w_out, const float* __restrict__ b_out,
    float2* __restrict__ pk)
{
    const int t = threadIdx.x;
    if (t < 12)       { int pp = t >> 1, c = t & 1;           float s = (pp < 4) ? SRZ : SN;
                        pk[t] = make_float2(s * w_ih_up[4*pp+c],  s * w_ih_up[4*pp+2+c]); }
    else if (t < 36)  { int i = t-12, pp = i >> 2, c = i & 3;  float s = (pp < 4) ? SRZ : SN;
                        pk[t] = make_float2(s * w_hh_up[8*pp+c],  s * w_hh_up[8*pp+4+c]); }
    else if (t < 60)  { int i = t-36, pp = i >> 2, c = i & 3;  float s = (pp < 4) ? SRZ : SN;
                        pk[t] = make_float2(s * w_ih_dn[8*pp+c],  s * w_ih_dn[8*pp+4+c]); }
    else if (t < 84)  { int i = t-60, pp = i >> 2, c = i & 3;  float s = (pp < 4) ? SRZ : SN;
                        pk[t] = make_float2(s * w_hh_dn[8*pp+c],  s * w_hh_dn[8*pp+4+c]); }
    else if (t < 100) { int i = t-84, pp = i >> 3, c = i & 7;
                        pk[t] = make_float2(SN * w1[16*pp+c],     SN * w1[16*pp+8+c]); }
    else if (t < 108) { int i = t-100, pp = i >> 2, c = i & 3;
                        pk[t] = make_float2(SN * w2[8*pp+c],      SN * w2[8*pp+4+c]); }
    else if (t < 112) { int p = t-108;
                        pk[t] = make_float2(SRZ * (b_ih_up[2*p]   + b_hh_up[2*p]),
                                            SRZ * (b_ih_up[2*p+1] + b_hh_up[2*p+1])); }
    else if (t < 116) { int p = t-112;
                        pk[t] = make_float2(SRZ * (b_ih_dn[2*p]   + b_hh_dn[2*p]),
                                            SRZ * (b_ih_dn[2*p+1] + b_hh_dn[2*p+1])); }
    else if (t < 118) { int p = t-116; pk[t] = make_float2(SN * b_ih_up[8+2*p], SN * b_ih_up[9+2*p]); }
    else if (t < 120) { int p = t-118; pk[t] = make_float2(SN * b_hh_up[8+2*p], SN * b_hh_up[9+2*p]); }
    else if (t < 122) { int p = t-120; pk[t] = make_float2(SN * b_ih_dn[8+2*p], SN * b_ih_dn[9+2*p]); }
    else if (t < 124) { int p = t-122; pk[t] = make_float2(SN * b_hh_dn[8+2*p], SN * b_hh_dn[9+2*p]); }
    else if (t < 126) { int p = t-124; pk[t] = make_float2(SN * b1[2*p], SN * b1[2*p+1]); }
    else if (t < 128) { int p = t-126; pk[t] = make_float2(SN * b2[2*p], SN * b2[2*p+1]); }
    else if (t == 128) pk[t] = make_float2(w_out[0], w_out[1]);
    else if (t == 129) pk[t] = make_float2(w_out[2], w_out[3]);
    else if (t == 130) pk[t] = make_float2(w_out[4], b_out[0]);
}

// acc += pair-packed 4-dot: wp[c] = {W[2pp][c], W[2pp+1][c]}, input (a.x,a.y,b.x,b.y)
__device__ __forceinline__ v2f dot4p(const v2f* __restrict__ wp, v2f a, v2f b, v2f acc) {
    acc = fma2(spl(a.x), wp[0], acc);
    acc = fma2(spl(a.y), wp[1], acc);
    acc = fma2(spl(b.x), wp[2], acc);
    acc = fma2(spl(b.y), wp[3], acc);
    return acc;
}

__global__ void __launch_bounds__(256) trec_kernel(
    const float* __restrict__ x, const PK* __restrict__ pk,
    float* __restrict__ out, int n)
{
    const int row = blockIdx.x * blockDim.x + threadIdx.x;
    if (row >= n) return;

    // ---- load 18-float row as 9x float2 ----
    float xv[18];
    {
        const float2* xp = reinterpret_cast<const float2*>(x + (size_t)row * 18u);
        #pragma unroll
        for (int k = 0; k < 9; ++k) {
            float2 v = xp[k];
            xv[2 * k] = v.x;
            xv[2 * k + 1] = v.y;
        }
    }

    v2f hA = spl(0.f), hB = spl(0.f);
    v2f hupA[7], hupB[7];

    // ---- up GRU: i = 6..0, xi = [j[i], jd[i]] ----
    #pragma unroll
    for (int s = 0; s < 7; ++s) {
        const int i = 6 - s;
        const v2f X0 = spl(xv[4 + i]);
        const v2f X1 = spl(xv[11 + i]);

        v2f rz[4];
        #pragma unroll
        for (int p = 0; p < 4; ++p) {          // pairs: rows (0,1),(2,3)=r; (4,5),(6,7)=z
            v2f acc = pk->bsu[p];
            acc = fma2(X0, pk->wiu[p][0], acc);
            acc = fma2(X1, pk->wiu[p][1], acc);
            acc = dot4p(pk->whu[p], hA, hB, acc);
            rz[p] = acc;
        }
        v2f rA = sig2s(rz[0]), rB = sig2s(rz[1]);
        v2f zA = sig2s(rz[2]), zB = sig2s(rz[3]);

        // n gates: rows (8,9),(10,11); gi and gh separate for r * gh
        v2f giA = fma2(X1, pk->wiu[4][1], fma2(X0, pk->wiu[4][0], pk->binu[0]));
        v2f giB = fma2(X1, pk->wiu[5][1], fma2(X0, pk->wiu[5][0], pk->binu[1]));
        v2f ghA = dot4p(pk->whu[4], hA, hB, pk->bhnu[0]);
        v2f ghB = dot4p(pk->whu[5], hA, hB, pk->bhnu[1]);
        v2f nA = tanh2s(fma2(rA, ghA, giA));
        v2f nB = tanh2s(fma2(rB, ghB, giB));

        hA = fma2(zA, hA - nA, nA);            // (1-z)*n + z*h
        hB = fma2(zB, hB - nB, nB);
        hupA[s] = hA; hupB[s] = hB;
    }

    // ---- MLP: tanh([obs,h] @ w1.T + b1) -> tanh(@ w2.T + b2) ----
    {
        float in8[8] = { xv[0], xv[1], xv[2], xv[3], hA.x, hA.y, hB.x, hB.y };
        v2f a0 = pk->b1p[0], a1 = pk->b1p[1];
        #pragma unroll
        for (int d = 0; d < 8; ++d) {
            a0 = fma2(spl(in8[d]), pk->w1p[0][d], a0);
            a1 = fma2(spl(in8[d]), pk->w1p[1][d], a1);
        }
        v2f t1A = tanh2s(a0), t1B = tanh2s(a1);
        v2f c0 = dot4p(pk->w2p[0], t1A, t1B, pk->b2p[0]);
        v2f c1 = dot4p(pk->w2p[1], t1A, t1B, pk->b2p[1]);
        hA = tanh2s(c0); hB = tanh2s(c1);
    }

    // ---- down GRU: i = 0..6, xi = hup[i]; act = [h, j[i]] @ w_out.T + b_out ----
    float acts[7];
    #pragma unroll
    for (int i = 0; i < 7; ++i) {
        const v2f xiA = hupA[i], xiB = hupB[i];

        v2f rz[4];
        #pragma unroll
        for (int p = 0; p < 4; ++p) {
            v2f acc = pk->bsd[p];
            acc = dot4p(pk->wid[p], xiA, xiB, acc);
            acc = dot4p(pk->whd[p], hA, hB, acc);
            rz[p] = acc;
        }
        v2f rA = sig2s(rz[0]), rB = sig2s(rz[1]);
        v2f zA = sig2s(rz[2]), zB = sig2s(rz[3]);

        v2f giA = dot4p(pk->wid[4], xiA, xiB, pk->bind[0]);
        v2f giB = dot4p(pk->wid[5], xiA, xiB, pk->bind[1]);
        v2f ghA = dot4p(pk->whd[4], hA, hB, pk->bhnd[0]);
        v2f ghB = dot4p(pk->whd[5], hA, hB, pk->bhnd[1]);
        v2f nA = tanh2s(fma2(rA, ghA, giA));
        v2f nB = tanh2s(fma2(rB, ghB, giB));

        hA = fma2(zA, hA - nA, nA);
        hB = fma2(zB, hB - nB, nB);

        v2f t = fma2(hA, pk->wo01, mk2(pk->wo4bo.y, 0.f));
        t = fma2(hB, pk->wo23, t);
        acts[i] = fmaf(xv[4 + i], pk->wo4bo.x, t.x + t.y);
    }

    // ---- store (n x 7, row-major) ----
    float* op = out + (size_t)row * 7u;
    #pragma unroll
    for (int i = 0; i < 7; ++i) op[i] = acts[i];
}

extern "C" void kernel_launch(void* const* d_in, const int* in_sizes, int n_in,
                              void* d_out, int out_size, void* d_ws, size_t ws_size,
                              hipStream_t stream)
{
    const float* x       = (const float*)d_in[0];
    const float* w_ih_up = (const float*)d_in[1];
    const float* w_hh_up = (const float*)d_in[2];
    const float* b_ih_up = (const float*)d_in[3];
    const float* b_hh_up = (const float*)d_in[4];
    const float* w1      = (const float*)d_in[5];
    const float* b1      = (const float*)d_in[6];
    const float* w2      = (const float*)d_in[7];
    const float* b2      = (const float*)d_in[8];
    const float* w_ih_dn = (const float*)d_in[9];
    const float* w_hh_dn = (const float*)d_in[10];
    const float* b_ih_dn = (const float*)d_in[11];
    const float* b_hh_dn = (const float*)d_in[12];
    const float* w_out   = (const float*)d_in[13];
    const float* b_out   = (const float*)d_in[14];
    float* out = (float*)d_out;

    const int n = in_sizes[0] / 18;
    const int block = 256;
    const int grid = (n + block - 1) / block;

    repack_kernel<<<1, 192, 0, stream>>>(
        w_ih_up, w_hh_up, b_ih_up, b_hh_up,
        w1, b1, w2, b2,
        w_ih_dn, w_hh_dn, b_ih_dn, b_hh_dn,
        w_out, b_out, (float2*)d_ws);

    trec_kernel<<<grid, block, 0, stream>>>(
        x, (const PK*)d_ws, out, n);
}

// Round 9
// 105.748 us; speedup vs baseline: 1.1066x; 1.0008x over previous
//
#include <hip/hip_runtime.h>

// TRecPolicy round 9: round-8 kernel + 4-way shared reciprocal per activation
// group (rA,rB / zA,zB / nA,nB / MLP pairs): 176 rcp -> 44 rcp, and the tanh
// x2 scale folded into the shared scalar (drops one pk_mul per tanh pair).

typedef float v2f __attribute__((ext_vector_type(2)));

__device__ __forceinline__ v2f mk2(float a, float b) { v2f r; r.x = a; r.y = b; return r; }
__device__ __forceinline__ v2f spl(float s) { return mk2(s, s); }
__device__ __forceinline__ v2f fma2(v2f a, v2f b, v2f c) { return __builtin_elementwise_fma(a, b, c); }

__device__ __forceinline__ float fexp2(float x) {
#if __has_builtin(__builtin_amdgcn_exp2f)
    return __builtin_amdgcn_exp2f(x);          // v_exp_f32 (2^x)
#else
    return __expf(0.6931471805599453f * x);
#endif
}
__device__ __forceinline__ float frcp(float x) { return __builtin_amdgcn_rcpf(x); }

#define LOG2E 1.44269504088896f

// PRE-SCALED activation groups: inputs are already -log2e*x (sig) / -2log2e*x
// (tanh). One v_rcp serves 4 denominators:
//   r = rcp(pA*pB), 1/dA = {dA.y,dA.x} * (pB*r), 1/dB = {dB.y,dB.x} * (pA*r)
__device__ __forceinline__ void sig4(v2f tA, v2f tB, v2f& oA, v2f& oB) {
    v2f eA = mk2(fexp2(tA.x), fexp2(tA.y));
    v2f eB = mk2(fexp2(tB.x), fexp2(tB.y));
    v2f dA = eA + spl(1.0f);
    v2f dB = eB + spl(1.0f);
    float pA = dA.x * dA.y, pB = dB.x * dB.y;
    float r  = frcp(pA * pB);
    oA = mk2(dA.y, dA.x) * spl(pB * r);
    oB = mk2(dB.y, dB.x) * spl(pA * r);
}
__device__ __forceinline__ void tanh4(v2f tA, v2f tB, v2f& oA, v2f& oB) {
    v2f eA = mk2(fexp2(tA.x), fexp2(tA.y));
    v2f eB = mk2(fexp2(tB.x), fexp2(tB.y));
    v2f dA = eA + spl(1.0f);
    v2f dB = eB + spl(1.0f);
    float pA = dA.x * dA.y, pB = dB.x * dB.y;
    float r2 = frcp(pA * pB) * 2.0f;           // fold tanh's x2 into the scalar
    oA = fma2(mk2(dA.y, dA.x), spl(pB * r2), spl(-1.0f));
    oB = fma2(mk2(dB.y, dB.x), spl(pA * r2), spl(-1.0f));
}

// Packed parameter block layout (all v2f, 131 total). Pair pp covers output
// rows (2pp, 2pp+1); element [pp][c] = scale * {W[2pp][c], W[2pp+1][c]}.
// Scales: gate rows 0..7 (r,z) -> -LOG2E; rows 8..11 (n) -> -2LOG2E;
//         w1/b1/w2/b2 -> -2LOG2E; w_out/b_out unscaled.
struct PK {
    v2f wiu[6][2];   // off   0: w_ih_up (12x2), scaled
    v2f whu[6][4];   // off  12: w_hh_up (12x4), scaled
    v2f wid[6][4];   // off  36: w_ih_dn (12x4), scaled
    v2f whd[6][4];   // off  60: w_hh_dn (12x4), scaled
    v2f w1p[2][8];   // off  84: w1 (4x8), scaled
    v2f w2p[2][4];   // off 100: w2 (4x4), scaled
    v2f bsu[4];      // off 108: (b_ih_up+b_hh_up) rows 0..7, scaled
    v2f bsd[4];      // off 112: (b_ih_dn+b_hh_dn) rows 0..7, scaled
    v2f binu[2];     // off 116: b_ih_up rows 8..11, scaled
    v2f bhnu[2];     // off 118: b_hh_up rows 8..11, scaled
    v2f bind[2];     // off 120: b_ih_dn rows 8..11, scaled
    v2f bhnd[2];     // off 122: b_hh_dn rows 8..11, scaled
    v2f b1p[2];      // off 124: scaled
    v2f b2p[2];      // off 126: scaled
    v2f wo01;        // off 128: {w_out[0], w_out[1]}
    v2f wo23;        // off 129: {w_out[2], w_out[3]}
    v2f wo4bo;       // off 130: {w_out[4], b_out[0]}
};

#define SRZ (-LOG2E)
#define SN  (-2.0f * LOG2E)

__global__ void repack_kernel(
    const float* __restrict__ w_ih_up, const float* __restrict__ w_hh_up,
    const float* __restrict__ b_ih_up, const float* __restrict__ b_hh_up,
    const float* __restrict__ w1, const float* __restrict__ b1,
    const float* __restrict__ w2, const float* __restrict__ b2,
    const float* __restrict__ w_ih_dn, const float* __restrict__ w_hh_dn,
    const float* __restrict__ b_ih_dn, const float* __restrict__ b_hh_dn,
    const float* __restrict__ w_out, const float* __restrict__ b_out,
    float2* __restrict__ pk)
{
    const int t = threadIdx.x;
    if (t < 12)       { int pp = t >> 1, c = t & 1;           float s = (pp < 4) ? SRZ : SN;
                        pk[t] = make_float2(s * w_ih_up[4*pp+c],  s * w_ih_up[4*pp+2+c]); }
    else if (t < 36)  { int i = t-12, pp = i >> 2, c = i & 3;  float s = (pp < 4) ? SRZ : SN;
                        pk[t] = make_float2(s * w_hh_up[8*pp+c],  s * w_hh_up[8*pp+4+c]); }
    else if (t < 60)  { int i = t-36, pp = i >> 2, c = i & 3;  float s = (pp < 4) ? SRZ : SN;
                        pk[t] = make_float2(s * w_ih_dn[8*pp+c],  s * w_ih_dn[8*pp+4+c]); }
    else if (t < 84)  { int i = t-60, pp = i >> 2, c = i & 3;  float s = (pp < 4) ? SRZ : SN;
                        pk[t] = make_float2(s * w_hh_dn[8*pp+c],  s * w_hh_dn[8*pp+4+c]); }
    else if (t < 100) { int i = t-84, pp = i >> 3, c = i & 7;
                        pk[t] = make_float2(SN * w1[16*pp+c],     SN * w1[16*pp+8+c]); }
    else if (t < 108) { int i = t-100, pp = i >> 2, c = i & 3;
                        pk[t] = make_float2(SN * w2[8*pp+c],      SN * w2[8*pp+4+c]); }
    else if (t < 112) { int p = t-108;
                        pk[t] = make_float2(SRZ * (b_ih_up[2*p]   + b_hh_up[2*p]),
                                            SRZ * (b_ih_up[2*p+1] + b_hh_up[2*p+1])); }
    else if (t < 116) { int p = t-112;
                        pk[t] = make_float2(SRZ * (b_ih_dn[2*p]   + b_hh_dn[2*p]),
                                            SRZ * (b_ih_dn[2*p+1] + b_hh_dn[2*p+1])); }
    else if (t < 118) { int p = t-116; pk[t] = make_float2(SN * b_ih_up[8+2*p], SN * b_ih_up[9+2*p]); }
    else if (t < 120) { int p = t-118; pk[t] = make_float2(SN * b_hh_up[8+2*p], SN * b_hh_up[9+2*p]); }
    else if (t < 122) { int p = t-120; pk[t] = make_float2(SN * b_ih_dn[8+2*p], SN * b_ih_dn[9+2*p]); }
    else if (t < 124) { int p = t-122; pk[t] = make_float2(SN * b_hh_dn[8+2*p], SN * b_hh_dn[9+2*p]); }
    else if (t < 126) { int p = t-124; pk[t] = make_float2(SN * b1[2*p], SN * b1[2*p+1]); }
    else if (t < 128) { int p = t-126; pk[t] = make_float2(SN * b2[2*p], SN * b2[2*p+1]); }
    else if (t == 128) pk[t] = make_float2(w_out[0], w_out[1]);
    else if (t == 129) pk[t] = make_float2(w_out[2], w_out[3]);
    else if (t == 130) pk[t] = make_float2(w_out[4], b_out[0]);
}

// acc += pair-packed 4-dot: wp[c] = {W[2pp][c], W[2pp+1][c]}, input (a.x,a.y,b.x,b.y)
__device__ __forceinline__ v2f dot4p(const v2f* __restrict__ wp, v2f a, v2f b, v2f acc) {
    acc = fma2(spl(a.x), wp[0], acc);
    acc = fma2(spl(a.y), wp[1], acc);
    acc = fma2(spl(b.x), wp[2], acc);
    acc = fma2(spl(b.y), wp[3], acc);
    return acc;
}

__global__ void __launch_bounds__(256) trec_kernel(
    const float* __restrict__ x, const PK* __restrict__ pk,
    float* __restrict__ out, int n)
{
    const int row = blockIdx.x * blockDim.x + threadIdx.x;
    if (row >= n) return;

    // ---- load 18-float row as 9x float2 ----
    float xv[18];
    {
        const float2* xp = reinterpret_cast<const float2*>(x + (size_t)row * 18u);
        #pragma unroll
        for (int k = 0; k < 9; ++k) {
            float2 v = xp[k];
            xv[2 * k] = v.x;
            xv[2 * k + 1] = v.y;
        }
    }

    v2f hA = spl(0.f), hB = spl(0.f);
    v2f hupA[7], hupB[7];

    // ---- up GRU: i = 6..0, xi = [j[i], jd[i]] ----
    #pragma unroll
    for (int s = 0; s < 7; ++s) {
        const int i = 6 - s;
        const v2f X0 = spl(xv[4 + i]);
        const v2f X1 = spl(xv[11 + i]);

        v2f rz[4];
        #pragma unroll
        for (int p = 0; p < 4; ++p) {          // pairs: rows (0,1),(2,3)=r; (4,5),(6,7)=z
            v2f acc = pk->bsu[p];
            acc = fma2(X0, pk->wiu[p][0], acc);
            acc = fma2(X1, pk->wiu[p][1], acc);
            acc = dot4p(pk->whu[p], hA, hB, acc);
            rz[p] = acc;
        }
        v2f rA, rB, zA, zB;
        sig4(rz[0], rz[1], rA, rB);
        sig4(rz[2], rz[3], zA, zB);

        // n gates: rows (8,9),(10,11); gi and gh separate for r * gh
        v2f giA = fma2(X1, pk->wiu[4][1], fma2(X0, pk->wiu[4][0], pk->binu[0]));
        v2f giB = fma2(X1, pk->wiu[5][1], fma2(X0, pk->wiu[5][0], pk->binu[1]));
        v2f ghA = dot4p(pk->whu[4], hA, hB, pk->bhnu[0]);
        v2f ghB = dot4p(pk->whu[5], hA, hB, pk->bhnu[1]);
        v2f nA, nB;
        tanh4(fma2(rA, ghA, giA), fma2(rB, ghB, giB), nA, nB);

        hA = fma2(zA, hA - nA, nA);            // (1-z)*n + z*h
        hB = fma2(zB, hB - nB, nB);
        hupA[s] = hA; hupB[s] = hB;
    }

    // ---- MLP: tanh([obs,h] @ w1.T + b1) -> tanh(@ w2.T + b2) ----
    {
        float in8[8] = { xv[0], xv[1], xv[2], xv[3], hA.x, hA.y, hB.x, hB.y };
        v2f a0 = pk->b1p[0], a1 = pk->b1p[1];
        #pragma unroll
        for (int d = 0; d < 8; ++d) {
            a0 = fma2(spl(in8[d]), pk->w1p[0][d], a0);
            a1 = fma2(spl(in8[d]), pk->w1p[1][d], a1);
        }
        v2f t1A, t1B;
        tanh4(a0, a1, t1A, t1B);
        v2f c0 = dot4p(pk->w2p[0], t1A, t1B, pk->b2p[0]);
        v2f c1 = dot4p(pk->w2p[1], t1A, t1B, pk->b2p[1]);
        tanh4(c0, c1, hA, hB);
    }

    // ---- down GRU: i = 0..6, xi = hup[i]; act = [h, j[i]] @ w_out.T + b_out ----
    float acts[7];
    #pragma unroll
    for (int i = 0; i < 7; ++i) {
        const v2f xiA = hupA[i], xiB = hupB[i];

        v2f rz[4];
        #pragma unroll
        for (int p = 0; p < 4; ++p) {
            v2f acc = pk->bsd[p];
            acc = dot4p(pk->wid[p], xiA, xiB, acc);
            acc = dot4p(pk->whd[p], hA, hB, acc);
            rz[p] = acc;
        }
        v2f rA, rB, zA, zB;
        sig4(rz[0], rz[1], rA, rB);
        sig4(rz[2], rz[3], zA, zB);

        v2f giA = dot4p(pk->wid[4], xiA, xiB, pk->bind[0]);
        v2f giB = dot4p(pk->wid[5], xiA, xiB, pk->bind[1]);
        v2f ghA = dot4p(pk->whd[4], hA, hB, pk->bhnd[0]);
        v2f ghB = dot4p(pk->whd[5], hA, hB, pk->bhnd[1]);
        v2f nA, nB;
        tanh4(fma2(rA, ghA, giA), fma2(rB, ghB, giB), nA, nB);

        hA = fma2(zA, hA - nA, nA);
        hB = fma2(zB, hB - nB, nB);

        v2f t = fma2(hA, pk->wo01, mk2(pk->wo4bo.y, 0.f));
        t = fma2(hB, pk->wo23, t);
        acts[i] = fmaf(xv[4 + i], pk->wo4bo.x, t.x + t.y);
    }

    // ---- store (n x 7, row-major) ----
    float* op = out + (size_t)row * 7u;
    #pragma unroll
    for (int i = 0; i < 7; ++i) op[i] = acts[i];
}

extern "C" void kernel_launch(void* const* d_in, const int* in_sizes, int n_in,
                              void* d_out, int out_size, void* d_ws, size_t ws_size,
                              hipStream_t stream)
{
    const float* x       = (const float*)d_in[0];
    const float* w_ih_up = (const float*)d_in[1];
    const float* w_hh_up = (const float*)d_in[2];
    const float* b_ih_up = (const float*)d_in[3];
    const float* b_hh_up = (const float*)d_in[4];
    const float* w1      = (const float*)d_in[5];
    const float* b1      = (const float*)d_in[6];
    const float* w2      = (const float*)d_in[7];
    const float* b2      = (const float*)d_in[8];
    const float* w_ih_dn = (const float*)d_in[9];
    const float* w_hh_dn = (const float*)d_in[10];
    const float* b_ih_dn = (const float*)d_in[11];
    const float* b_hh_dn = (const float*)d_in[12];
    const float* w_out   = (const float*)d_in[13];
    const float* b_out   = (const float*)d_in[14];
    float* out = (float*)d_out;

    const int n = in_sizes[0] / 18;
    const int block = 256;
    const int grid = (n + block - 1) / block;

    repack_kernel<<<1, 192, 0, stream>>>(
        w_ih_up, w_hh_up, b_ih_up, b_hh_up,
        w1, b1, w2, b2,
        w_ih_dn, w_hh_dn, b_ih_dn, b_hh_dn,
        w_out, b_out, (float2*)d_ws);

    trec_kernel<<<grid, block, 0, stream>>>(
        x, (const PK*)d_ws, out, n);
}